// Round 3
// baseline (13297.012 us; speedup 1.0000x reference)
//
#include <hip/hip_runtime.h>
#include <math.h>

#define Bq   128
#define Tt   128
#define Dd   512
#define Hh   8
#define DHh  64
#define FFf  2048
#define Ee   4
#define MT   (Bq*Tt)     // 16384 tokens
#define LN_EPS 1e-5f
#define SCALE  0.125f    // 64^-0.5

// ---------------------------------------------------------------------------
// Embedding table: table[v][d] = sum_f cbfv[v][f] * Wemb[f][d] + bemb[d]
__global__ __launch_bounds__(256) void emb_table_kernel(
    const float* __restrict__ cbfv, const float* __restrict__ Wemb,
    const float* __restrict__ bemb, float* __restrict__ table)
{
    const int idx = blockIdx.x * 256 + threadIdx.x;   // < 120*512 = 61440
    const int vr = idx >> 9, d = idx & 511;
    float s = bemb[d];
    const float* crow = cbfv + vr * 200;
    for (int f = 0; f < 200; ++f) s += crow[f] * Wemb[f * 512 + d];
    table[idx] = s;
}

// x[tok][:] = table[src[tok]][:]   (float4 granularity)
__global__ __launch_bounds__(256) void gather_kernel(
    const int* __restrict__ src, const float* __restrict__ table,
    float* __restrict__ x)
{
    const int idx = blockIdx.x * 256 + threadIdx.x;   // < MT*128
    const int tok = idx >> 7, j = idx & 127;
    ((float4*)x)[idx] = ((const float4*)table)[src[tok] * 128 + j];
}

// bias[b][r][c] = alpha * log1p(|frac[b,r]-frac[b,c]|) * sign(diff)
__global__ __launch_bounds__(256) void bias_kernel(
    const float* __restrict__ frac, const float* __restrict__ alpha_p,
    float* __restrict__ biasb)
{
    const int idx = blockIdx.x * 256 + threadIdx.x;   // < B*T*T = 2097152
    const int b = idx >> 14;
    const int r = (idx >> 7) & 127;
    const int c = idx & 127;
    const float diff = frac[(b << 7) + r] - frac[(b << 7) + c];
    const float sg = (diff > 0.f) ? 1.f : ((diff < 0.f) ? -1.f : 0.f);
    biasb[idx] = alpha_p[0] * log1pf(fabsf(diff)) * sg;
}

// ---------------------------------------------------------------------------
// Generic fp32 GEMM: C[M,N] = A[M,K] @ W[K,N] + bias[N], tile 128x128x16,
// 256 threads, 8x8 micro-tile as 2x2 float4 blocks.
// EPI: 0 = store, 1 = store relu, 2 = C += w_row*val, 3 = C = w_row*val
template<int EPI>
__global__ __launch_bounds__(256) void gemm_f32(
    const float* __restrict__ A, const float* __restrict__ W,
    const float* __restrict__ bias, float* __restrict__ C,
    const int M, const int N, const int K,
    const float* __restrict__ rowscale, const int rs_stride)
{
    __shared__ float As[16][128];   // transposed: As[k][m]
    __shared__ float Bs[16][128];   // Bs[k][n]
    const int tid = threadIdx.x;
    const int tx = tid & 15, ty = tid >> 4;
    const int m0 = blockIdx.y * 128, n0 = blockIdx.x * 128;
    const int ar  = tid >> 2;           // 0..63  (A tile row)
    const int akq = (tid & 3) * 4;      // k-quad start
    const int bkr = tid >> 5;           // 0..7   (B tile k-row)
    const int bnq = (tid & 31) * 4;     // n-quad start

    float acc[2][2][4][4] = {};
    const float* Aptr  = A + (size_t)(m0 + ar) * K + akq;
    const float* Aptr2 = Aptr + (size_t)64 * K;
    const float* Wptr  = W + (size_t)bkr * N + n0 + bnq;
    const float* Wptr2 = Wptr + (size_t)8 * N;

    for (int k0 = 0; k0 < K; k0 += 16) {
        const float4 la0 = *(const float4*)(Aptr  + k0);
        const float4 la1 = *(const float4*)(Aptr2 + k0);
        const float4 lb0 = *(const float4*)(Wptr  + (size_t)k0 * N);
        const float4 lb1 = *(const float4*)(Wptr2 + (size_t)k0 * N);
        __syncthreads();   // previous compute done before overwriting LDS
        As[akq+0][ar] = la0.x; As[akq+1][ar] = la0.y;
        As[akq+2][ar] = la0.z; As[akq+3][ar] = la0.w;
        As[akq+0][ar+64] = la1.x; As[akq+1][ar+64] = la1.y;
        As[akq+2][ar+64] = la1.z; As[akq+3][ar+64] = la1.w;
        *(float4*)&Bs[bkr  ][bnq] = lb0;
        *(float4*)&Bs[bkr+8][bnq] = lb1;
        __syncthreads();
        #pragma unroll
        for (int kk = 0; kk < 16; ++kk) {
            const float4 av0 = *(const float4*)&As[kk][ty*4];
            const float4 av1 = *(const float4*)&As[kk][64 + ty*4];
            const float4 bv0 = *(const float4*)&Bs[kk][tx*4];
            const float4 bv1 = *(const float4*)&Bs[kk][64 + tx*4];
            const float am[2][4] = {{av0.x,av0.y,av0.z,av0.w},
                                    {av1.x,av1.y,av1.z,av1.w}};
            const float bn[2][4] = {{bv0.x,bv0.y,bv0.z,bv0.w},
                                    {bv1.x,bv1.y,bv1.z,bv1.w}};
            #pragma unroll
            for (int mi = 0; mi < 2; ++mi)
            #pragma unroll
            for (int i = 0; i < 4; ++i)
            #pragma unroll
            for (int ni = 0; ni < 2; ++ni)
            #pragma unroll
            for (int j = 0; j < 4; ++j)
                acc[mi][ni][i][j] += am[mi][i] * bn[ni][j];
        }
    }

    #pragma unroll
    for (int mi = 0; mi < 2; ++mi)
    #pragma unroll
    for (int i = 0; i < 4; ++i) {
        const int row = m0 + mi*64 + ty*4 + i;
        float wr = 0.f;
        if (EPI >= 2) wr = rowscale[(size_t)row * rs_stride];
        #pragma unroll
        for (int ni = 0; ni < 2; ++ni) {
            const int cn = n0 + ni*64 + tx*4;
            const float4 bv = *(const float4*)(bias + cn);
            float4 val;
            val.x = acc[mi][ni][i][0] + bv.x;
            val.y = acc[mi][ni][i][1] + bv.y;
            val.z = acc[mi][ni][i][2] + bv.z;
            val.w = acc[mi][ni][i][3] + bv.w;
            if (EPI == 1) {
                val.x = fmaxf(val.x, 0.f); val.y = fmaxf(val.y, 0.f);
                val.z = fmaxf(val.z, 0.f); val.w = fmaxf(val.w, 0.f);
            }
            float* cp = C + (size_t)row * N + cn;
            if (EPI == 0 || EPI == 1) {
                *(float4*)cp = val;
            } else if (EPI == 3) {
                float4 ov;
                ov.x = wr*val.x; ov.y = wr*val.y;
                ov.z = wr*val.z; ov.w = wr*val.w;
                *(float4*)cp = ov;
            } else {
                float4 old = *(const float4*)cp;
                old.x += wr*val.x; old.y += wr*val.y;
                old.z += wr*val.z; old.w += wr*val.w;
                *(float4*)cp = old;
            }
        }
    }
}

// ---------------------------------------------------------------------------
// Attention: one block per (b,h). K staged in LDS (padded +1), 2 q-rows per
// iteration (256 thr = 2 rows x 128 cols), wave-level softmax over 64 lanes.
__global__ __launch_bounds__(256) void attn_kernel(
    const float* __restrict__ q, const float* __restrict__ k,
    const float* __restrict__ v, const float* __restrict__ biasb,
    const int* __restrict__ src, float* __restrict__ out)
{
    const int bh = blockIdx.x;
    const int b = bh >> 3, h = bh & 7;
    const int tid = threadIdx.x;
    const int tr = tid >> 7, tc = tid & 127;
    __shared__ float k_lds[Tt][DHh + 1];
    __shared__ float q_lds[2][DHh];
    __shared__ float sc[2][Tt];
    __shared__ float maskv[Tt];

    for (int idx = tid; idx < Tt * DHh; idx += 256) {
        const int r = idx >> 6, d = idx & 63;
        k_lds[r][d] = k[(size_t)(b*Tt + r) * Dd + h*DHh + d];
    }
    if (tid < Tt)
        maskv[tid] = (src[b*Tt + tid] == 0) ? -__builtin_inff() : 0.0f;
    __syncthreads();

    for (int qp = 0; qp < Tt/2; ++qp) {
        if (tid < 128) {
            const int tr2 = tid >> 6, d = tid & 63;
            q_lds[tr2][d] = q[(size_t)(b*Tt + qp*2 + tr2) * Dd + h*DHh + d];
        }
        __syncthreads();
        const int r = qp*2 + tr;
        float s = 0.f;
        #pragma unroll
        for (int d = 0; d < DHh; ++d) s += q_lds[tr][d] * k_lds[tc][d];
        s = s * SCALE + biasb[((size_t)(b*Tt) + r) * Tt + tc] + maskv[tc];
        sc[tr][tc] = s;
        __syncthreads();
        if (tc < 64) {   // waves 0 and 2: softmax + PV for their q-row
            float s0 = sc[tr][tc], s1 = sc[tr][tc + 64];
            float m = fmaxf(s0, s1);
            for (int mm = 32; mm >= 1; mm >>= 1) m = fmaxf(m, __shfl_xor(m, mm));
            const float e0 = expf(s0 - m), e1 = expf(s1 - m);
            sc[tr][tc] = e0; sc[tr][tc + 64] = e1;
            float ssum = e0 + e1;
            for (int mm = 32; mm >= 1; mm >>= 1) ssum += __shfl_xor(ssum, mm);
            const float inv = 1.0f / ssum;
            const float* vb = v + (size_t)(b*Tt) * Dd + h*DHh + tc;  // d = tc
            float acc = 0.f;
            #pragma unroll 4
            for (int j = 0; j < Tt; ++j) acc += sc[tr][j] * vb[(size_t)j * Dd];
            out[(size_t)(b*Tt + r) * Dd + h*DHh + tc] = acc * inv;
        }
        __syncthreads();
    }
}

// ---------------------------------------------------------------------------
// out = LayerNorm(x + res) * g + b  — one wave per token
__global__ __launch_bounds__(256) void add_ln_kernel(
    const float* __restrict__ xin, const float* __restrict__ res,
    const float* __restrict__ g, const float* __restrict__ bb,
    float* __restrict__ outp)
{
    const int tid = threadIdx.x;
    const int token = blockIdx.x * 4 + (tid >> 6);
    const int lane = tid & 63;
    const float* xr = xin + (size_t)token * Dd + lane * 8;
    const float* rr = res + (size_t)token * Dd + lane * 8;
    const float4 a0 = *(const float4*)xr;
    const float4 a1 = *(const float4*)(xr + 4);
    const float4 r0 = *(const float4*)rr;
    const float4 r1 = *(const float4*)(rr + 4);
    const float v0 = a0.x+r0.x, v1 = a0.y+r0.y, v2 = a0.z+r0.z, v3 = a0.w+r0.w;
    const float v4 = a1.x+r1.x, v5 = a1.y+r1.y, v6 = a1.z+r1.z, v7 = a1.w+r1.w;
    float s1 = v0+v1+v2+v3+v4+v5+v6+v7;
    float s2 = v0*v0+v1*v1+v2*v2+v3*v3+v4*v4+v5*v5+v6*v6+v7*v7;
    for (int mm = 32; mm >= 1; mm >>= 1) {
        s1 += __shfl_xor(s1, mm);
        s2 += __shfl_xor(s2, mm);
    }
    const float mean = s1 * (1.0f / Dd);
    const float var  = s2 * (1.0f / Dd) - mean * mean;
    const float rstd = 1.0f / sqrtf(var + LN_EPS);
    const float4 g0 = *(const float4*)(g + lane*8);
    const float4 g1 = *(const float4*)(g + lane*8 + 4);
    const float4 b0 = *(const float4*)(bb + lane*8);
    const float4 b1 = *(const float4*)(bb + lane*8 + 4);
    float4 o0, o1;
    o0.x = (v0-mean)*rstd*g0.x + b0.x; o0.y = (v1-mean)*rstd*g0.y + b0.y;
    o0.z = (v2-mean)*rstd*g0.z + b0.z; o0.w = (v3-mean)*rstd*g0.w + b0.w;
    o1.x = (v4-mean)*rstd*g1.x + b1.x; o1.y = (v5-mean)*rstd*g1.y + b1.y;
    o1.z = (v6-mean)*rstd*g1.z + b1.z; o1.w = (v7-mean)*rstd*g1.w + b1.w;
    *(float4*)(outp + (size_t)token * Dd + lane*8)     = o0;
    *(float4*)(outp + (size_t)token * Dd + lane*8 + 4) = o1;
}

// ---------------------------------------------------------------------------
// gates = softmax(x @ Wg + bg) over E=4; keep top-2 (no renormalization),
// tie-breaking = lowest index first (matches jax.lax.top_k).
__global__ __launch_bounds__(256) void gates_kernel(
    const float* __restrict__ x, const float* __restrict__ Wg,
    const float* __restrict__ bgp, float* __restrict__ w)
{
    const int tid = threadIdx.x;
    const int token = blockIdx.x * 4 + (tid >> 6);
    const int lane = tid & 63;
    const float4* Wg4 = (const float4*)Wg;
    const float* xr = x + (size_t)token * Dd;
    float a0 = 0, a1 = 0, a2 = 0, a3 = 0;
    #pragma unroll
    for (int i = 0; i < Dd/64; ++i) {
        const int d = lane + i*64;
        const float xv = xr[d];
        const float4 wv = Wg4[d];
        a0 += xv*wv.x; a1 += xv*wv.y; a2 += xv*wv.z; a3 += xv*wv.w;
    }
    for (int mm = 32; mm >= 1; mm >>= 1) {
        a0 += __shfl_xor(a0, mm); a1 += __shfl_xor(a1, mm);
        a2 += __shfl_xor(a2, mm); a3 += __shfl_xor(a3, mm);
    }
    if (lane == 0) {
        float p[4] = {a0 + bgp[0], a1 + bgp[1], a2 + bgp[2], a3 + bgp[3]};
        const float mx = fmaxf(fmaxf(p[0], p[1]), fmaxf(p[2], p[3]));
        float s = 0.f;
        #pragma unroll
        for (int e = 0; e < 4; ++e) { p[e] = expf(p[e] - mx); s += p[e]; }
        const float invs = 1.0f / s;
        #pragma unroll
        for (int e = 0; e < 4; ++e) p[e] *= invs;
        int i1 = 0; float bv1 = p[0];
        for (int e = 1; e < 4; ++e) if (p[e] > bv1) { bv1 = p[e]; i1 = e; }
        int i2 = -1; float bv2 = -1.f;
        for (int e = 0; e < 4; ++e)
            if (e != i1 && p[e] > bv2) { bv2 = p[e]; i2 = e; }
        float4 ow;
        ow.x = (i1 == 0 || i2 == 0) ? p[0] : 0.f;
        ow.y = (i1 == 1 || i2 == 1) ? p[1] : 0.f;
        ow.z = (i1 == 2 || i2 == 2) ? p[2] : 0.f;
        ow.w = (i1 == 3 || i2 == 3) ? p[3] : 0.f;
        *(float4*)(w + (size_t)token * 4) = ow;
    }
}

// ---------------------------------------------------------------------------
extern "C" void kernel_launch(void* const* d_in, const int* in_sizes, int n_in,
                              void* d_out, int out_size, void* d_ws, size_t ws_size,
                              hipStream_t stream)
{
    (void)in_sizes; (void)n_in; (void)out_size; (void)ws_size;
    const int*   src   = (const int*)d_in[0];
    const float* frac  = (const float*)d_in[1];
    const float* cbfv  = (const float*)d_in[2];
    const float* Wemb  = (const float*)d_in[3];
    const float* bemb  = (const float*)d_in[4];
    const float* Wq    = (const float*)d_in[5];
    const float* bq    = (const float*)d_in[6];
    const float* Wk    = (const float*)d_in[7];
    const float* bk    = (const float*)d_in[8];
    const float* Wv    = (const float*)d_in[9];
    const float* bv    = (const float*)d_in[10];
    const float* Wo    = (const float*)d_in[11];
    const float* bo    = (const float*)d_in[12];
    const float* alpha = (const float*)d_in[13];
    const float* ln1g  = (const float*)d_in[14];
    const float* ln1b  = (const float*)d_in[15];
    const float* ln2g  = (const float*)d_in[16];
    const float* ln2b  = (const float*)d_in[17];
    const float* Wg    = (const float*)d_in[18];
    const float* bg    = (const float*)d_in[19];
    const float* W1    = (const float*)d_in[20];
    const float* b1    = (const float*)d_in[21];
    const float* W2    = (const float*)d_in[22];
    const float* b2    = (const float*)d_in[23];
    float* out = (float*)d_out;

    char* ws = (char*)d_ws;
    size_t o = 0;
    auto alloc = [&](size_t bytes) -> float* {
        char* p = ws + o;
        o += (bytes + 255) & ~(size_t)255;
        return (float*)p;
    };
    float* table = alloc((size_t)120 * 512 * 4);
    float* x     = alloc((size_t)MT * Dd * 4);
    float* qbuf  = alloc((size_t)MT * Dd * 4);   // contiguous 4-buffer region,
    float* kbuf  = alloc((size_t)MT * Dd * 4);   // reused as MoE h buffer
    float* vbuf  = alloc((size_t)MT * Dd * 4);   // (4 * MT*D*4 == MT*FF*4)
    float* attnb = alloc((size_t)MT * Dd * 4);
    float* proj  = alloc((size_t)MT * Dd * 4);   // reused as ff buffer
    float* biasb = alloc((size_t)Bq * Tt * Tt * 4);
    float* wbuf  = alloc((size_t)MT * Ee * 4);
    float* hbuf  = qbuf;   // q/k/v/attn dead during MoE phase
    float* ffb   = proj;   // proj dead after ln1

    emb_table_kernel<<<240, 256, 0, stream>>>(cbfv, Wemb, bemb, table);
    gather_kernel<<<8192, 256, 0, stream>>>(src, table, x);
    bias_kernel<<<8192, 256, 0, stream>>>(frac, alpha, biasb);

    for (int layer = 0; layer < 3; ++layer) {
        gemm_f32<0><<<dim3(4,128), 256, 0, stream>>>(x, Wq, bq, qbuf, MT, 512, 512, nullptr, 0);
        gemm_f32<0><<<dim3(4,128), 256, 0, stream>>>(x, Wk, bk, kbuf, MT, 512, 512, nullptr, 0);
        gemm_f32<0><<<dim3(4,128), 256, 0, stream>>>(x, Wv, bv, vbuf, MT, 512, 512, nullptr, 0);
        attn_kernel<<<Bq*Hh, 256, 0, stream>>>(qbuf, kbuf, vbuf, biasb, src, attnb);
        gemm_f32<0><<<dim3(4,128), 256, 0, stream>>>(attnb, Wo, bo, proj, MT, 512, 512, nullptr, 0);
        add_ln_kernel<<<4096, 256, 0, stream>>>(x, proj, ln1g, ln1b, x);
        gates_kernel<<<4096, 256, 0, stream>>>(x, Wg, bg, wbuf);
        for (int e = 0; e < Ee; ++e) {
            gemm_f32<1><<<dim3(16,128), 256, 0, stream>>>(
                x, W1 + (size_t)e * Dd * FFf, b1 + e * FFf, hbuf, MT, FFf, Dd, nullptr, 0);
            if (e == 0)
                gemm_f32<3><<<dim3(4,128), 256, 0, stream>>>(
                    hbuf, W2 + (size_t)e * FFf * Dd, b2 + e * Dd, ffb, MT, Dd, FFf, wbuf + e, Ee);
            else
                gemm_f32<2><<<dim3(4,128), 256, 0, stream>>>(
                    hbuf, W2 + (size_t)e * FFf * Dd, b2 + e * Dd, ffb, MT, Dd, FFf, wbuf + e, Ee);
        }
        float* dst = (layer == 2) ? out : x;
        add_ln_kernel<<<4096, 256, 0, stream>>>(x, ffb, ln2g, ln2b, dst);
    }
}

// Round 9
// 7663.016 us; speedup vs baseline: 1.7352x; 1.7352x over previous
//
#include <hip/hip_runtime.h>
#include <math.h>

#define Bq   128
#define Tt   128
#define Dd   512
#define Hh   8
#define DHh  64
#define FFf  2048
#define Ee   4
#define MT   (Bq*Tt)     // 16384 tokens
#define CHM  (MT/2)      // 8192-token chunk (64 batches)
#define LN_EPS 1e-5f
#define SCALE  0.125f    // 64^-0.5

typedef unsigned short u16;
typedef unsigned int   u32;
typedef __attribute__((ext_vector_type(8))) short short8;
typedef __attribute__((ext_vector_type(4))) float f32x4;
typedef __attribute__((ext_vector_type(4))) u16   u16x4;

__device__ __forceinline__ u16 f2bf(float f) {          // RNE f32->bf16
    u32 u = __builtin_bit_cast(u32, f);
    u32 r = (u + 0x7FFFu + ((u >> 16) & 1u)) >> 16;
    return (u16)r;
}
__device__ __forceinline__ float bf2f(u16 h) {
    u32 u = ((u32)h) << 16;
    return __builtin_bit_cast(float, u);
}
// split f32 into hi/lo bf16: f ~= hi + lo, err ~ 2^-17 |f|
struct bfpair { u16 h, l; };
__device__ __forceinline__ bfpair splitbf(float f) {
    bfpair p;
    p.h = f2bf(f);
    p.l = f2bf(f - bf2f(p.h));
    return p;
}
__device__ __forceinline__ void gload_lds16(const void* g, void* l) {
    __builtin_amdgcn_global_load_lds(
        (const __attribute__((address_space(1))) u32*)g,
        (__attribute__((address_space(3))) u32*)l, 16, 0, 0);
}

// ---------------------------------------------------------------------------
// table[v][d] = sum_f cbfv[v][f] * Wemb[f][d] + bemb[d]
__global__ __launch_bounds__(256) void emb_table_kernel(
    const float* __restrict__ cbfv, const float* __restrict__ Wemb,
    const float* __restrict__ bemb, float* __restrict__ table)
{
    const int idx = blockIdx.x * 256 + threadIdx.x;   // < 120*512
    const int vr = idx >> 9, d = idx & 511;
    float s = bemb[d];
    const float* crow = cbfv + vr * 200;
    for (int f = 0; f < 200; ++f) s += crow[f] * Wemb[f * 512 + d];
    table[idx] = s;
}

// x split[tok][:] = split(table[src[tok]][:])
__global__ __launch_bounds__(256) void gather_kernel(
    const int* __restrict__ src, const float* __restrict__ table,
    u16* __restrict__ xh, u16* __restrict__ xl)
{
    const int idx = blockIdx.x * 256 + threadIdx.x;   // < MT*128
    const int tok = idx >> 7;
    const float4 tv = ((const float4*)table)[src[tok] * 128 + (idx & 127)];
    const bfpair px = splitbf(tv.x), py = splitbf(tv.y);
    const bfpair pz = splitbf(tv.z), pw = splitbf(tv.w);
    u16x4 hbv, lbv;
    hbv.x = px.h; hbv.y = py.h; hbv.z = pz.h; hbv.w = pw.h;
    lbv.x = px.l; lbv.y = py.l; lbv.z = pz.l; lbv.w = pw.l;
    ((u16x4*)xh)[idx] = hbv;
    ((u16x4*)xl)[idx] = lbv;
}

// bias[b][r][c] = alpha * log1p(|diff|) * sign(diff)
__global__ __launch_bounds__(256) void bias_kernel(
    const float* __restrict__ frac, const float* __restrict__ alpha_p,
    float* __restrict__ biasb)
{
    const int idx = blockIdx.x * 256 + threadIdx.x;   // < B*T*T
    const int b = idx >> 14;
    const int r = (idx >> 7) & 127;
    const int c = idx & 127;
    const float diff = frac[(b << 7) + r] - frac[(b << 7) + c];
    const float sg = (diff > 0.f) ? 1.f : ((diff < 0.f) ? -1.f : 0.f);
    biasb[idx] = alpha_p[0] * log1pf(fabsf(diff)) * sg;
}

// in[Kd][Nd] f32 -> out{h,l}[Nd][Kd] split bf16 (tiled via LDS)
__global__ __launch_bounds__(256) void transpose_split(
    const float* __restrict__ in, u16* __restrict__ outh,
    u16* __restrict__ outl, const int Kd, const int Nd)
{
    __shared__ float tb[32][33];
    const int tx = threadIdx.x, ty = threadIdx.y;   // 32 x 8
    const int kt = blockIdx.y * 32, nt = blockIdx.x * 32;
    #pragma unroll
    for (int s = 0; s < 4; ++s)
        tb[ty + 8*s][tx] = in[(size_t)(kt + ty + 8*s) * Nd + nt + tx];
    __syncthreads();
    #pragma unroll
    for (int s = 0; s < 4; ++s) {
        const bfpair p = splitbf(tb[tx][ty + 8*s]);
        const size_t o = (size_t)(nt + ty + 8*s) * Kd + kt + tx;
        outh[o] = p.h;
        outl[o] = p.l;
    }
}

// ---------------------------------------------------------------------------
// Split-bf16 3-pass MFMA GEMM (Markidis): C = (Ah+Al)@(Bh+Bl)^T + bias
//   ~= Ah@Bh + Ah@Bl + Al@Bh  (error ~2^-16, fp32-class)
// A{h,l}[M][K], B{h,l}[N][K] bf16. Tile 128x128, BK=64, 4 waves (2x2),
// mfma_f32_16x16x32_bf16. Fragment-ordered linear LDS: staging dest
// (wave base + lane*16) == ds_read_b128 fragment address; no swizzle.
// EPI: 0 f32 store | 1 relu->split bf16 (Cv=hi, Cv2=lo) | 2 f32 += w*val
//      | 3 f32 = w*val
template<int EPI>
__global__ __launch_bounds__(256) void gemm_split(
    const u16* __restrict__ Ah, const u16* __restrict__ Al,
    const u16* __restrict__ Bh, const u16* __restrict__ Bl,
    const float* __restrict__ bias, void* __restrict__ Cv,
    u16* __restrict__ Cv2,
    const int M, const int N, const int K,
    const float* __restrict__ rowscale, const int rs_stride)
{
    __shared__ u16 AHs[8192];   // 16 KB each: [8 grp][2 t][64 lane][8 bf16]
    __shared__ u16 ALs[8192];
    __shared__ u16 BHs[8192];
    __shared__ u16 BLs[8192];
    const int tid = threadIdx.x;
    const int lane = tid & 63, wid = tid >> 6;
    const int m0 = blockIdx.y * 128, n0 = blockIdx.x * 128;

    // staging source: linear 16B-unit u -> (group,row,k-slot)
    u32 offA[4], offB[4];
    #pragma unroll
    for (int i = 0; i < 4; ++i) {
        const int u = i * 256 + tid;
        const int g = u >> 7, w = u & 127, t = w >> 6, p = w & 63;
        const int row = g * 16 + (p & 15);
        const int kc  = (t * 4 + (p >> 4)) * 8;
        offA[i] = (u32)(m0 + row) * K + kc;
        offB[i] = (u32)(n0 + row) * K + kc;
    }
    const int ldsoff = wid * 1024;   // wave-uniform dest base (+lane*16 by HW)

    f32x4 acc[4][4];
    #pragma unroll
    for (int m = 0; m < 4; ++m)
        #pragma unroll
        for (int n = 0; n < 4; ++n) acc[m][n] = (f32x4){0.f, 0.f, 0.f, 0.f};
    const int wr = wid >> 1, wc = wid & 1;

    for (int k0 = 0; k0 < K; k0 += 64) {
        __syncthreads();             // prev compute done before overwrite
        #pragma unroll
        for (int i = 0; i < 4; ++i) {
            gload_lds16(Ah + offA[i], (char*)AHs + i * 4096 + ldsoff);
            gload_lds16(Al + offA[i], (char*)ALs + i * 4096 + ldsoff);
            gload_lds16(Bh + offB[i], (char*)BHs + i * 4096 + ldsoff);
            gload_lds16(Bl + offB[i], (char*)BLs + i * 4096 + ldsoff);
            offA[i] += 64; offB[i] += 64;
        }
        __syncthreads();             // barrier drains vmcnt(0)
        short8 fah[4][2], fal[4][2], fbh[4][2], fbl[4][2];
        #pragma unroll
        for (int m = 0; m < 4; ++m)
            #pragma unroll
            for (int t = 0; t < 2; ++t) {
                const int ao = (wr*4 + m)*1024 + t*512 + lane*8;
                const int bo = (wc*4 + m)*1024 + t*512 + lane*8;
                fah[m][t] = *(const short8*)(AHs + ao);
                fal[m][t] = *(const short8*)(ALs + ao);
                fbh[m][t] = *(const short8*)(BHs + bo);
                fbl[m][t] = *(const short8*)(BLs + bo);
            }
        #pragma unroll
        for (int t = 0; t < 2; ++t)
            #pragma unroll
            for (int m = 0; m < 4; ++m)
                #pragma unroll
                for (int n = 0; n < 4; ++n) {
                    acc[m][n] = __builtin_amdgcn_mfma_f32_16x16x32_bf16(
                        fah[m][t], fbh[n][t], acc[m][n], 0, 0, 0);
                    acc[m][n] = __builtin_amdgcn_mfma_f32_16x16x32_bf16(
                        fah[m][t], fbl[n][t], acc[m][n], 0, 0, 0);
                    acc[m][n] = __builtin_amdgcn_mfma_f32_16x16x32_bf16(
                        fal[m][t], fbh[n][t], acc[m][n], 0, 0, 0);
                }
    }

    // epilogue: C/D layout col = lane&15, row = (lane>>4)*4 + reg
    const int rbase = m0 + wr * 64 + ((lane >> 4) << 2);
    const int cbase = n0 + wc * 64 + (lane & 15);
    #pragma unroll
    for (int m = 0; m < 4; ++m) {
        #pragma unroll
        for (int n = 0; n < 4; ++n) {
            const int col = cbase + n * 16;
            const float bc = bias[col];
            #pragma unroll
            for (int r = 0; r < 4; ++r) {
                const int row = rbase + m * 16 + r;
                const float v = acc[m][n][r] + bc;
                if (EPI == 0) {
                    ((float*)Cv)[(size_t)row * N + col] = v;
                } else if (EPI == 1) {
                    const bfpair p = splitbf(fmaxf(v, 0.f));
                    ((u16*)Cv)[(size_t)row * N + col] = p.h;
                    Cv2[(size_t)row * N + col] = p.l;
                } else if (EPI == 3) {
                    const float wrs = rowscale[(size_t)row * rs_stride];
                    ((float*)Cv)[(size_t)row * N + col] = wrs * v;
                } else {
                    const float wrs = rowscale[(size_t)row * rs_stride];
                    ((float*)Cv)[(size_t)row * N + col] += wrs * v;
                }
            }
        }
    }
}

// ---------------------------------------------------------------------------
// Attention on a 64-batch chunk: q/k/v are chunk-local f32 [CHM][D];
// biasb/src/out indexed globally via batch offset b0. Writes split-bf16 out.
__global__ __launch_bounds__(256) void attn_kernel(
    const float* __restrict__ q, const float* __restrict__ k,
    const float* __restrict__ v, const float* __restrict__ biasb,
    const int* __restrict__ src, u16* __restrict__ outh,
    u16* __restrict__ outl, const int b0)
{
    const int bh = blockIdx.x;            // < 64*8
    const int bl = bh >> 3, h = bh & 7;   // chunk-local batch
    const int bg = b0 + bl;               // global batch
    const int tid = threadIdx.x;
    const int tr = tid >> 7, tc = tid & 127;
    __shared__ float k_lds[Tt][DHh + 1];
    __shared__ float q_lds[2][DHh];
    __shared__ float sc[2][Tt];
    __shared__ float maskv[Tt];

    for (int idx = tid; idx < Tt * DHh; idx += 256) {
        const int r = idx >> 6, d = idx & 63;
        k_lds[r][d] = k[(size_t)(bl*Tt + r) * Dd + h*DHh + d];
    }
    if (tid < Tt)
        maskv[tid] = (src[bg*Tt + tid] == 0) ? -__builtin_inff() : 0.0f;
    __syncthreads();

    for (int qp = 0; qp < Tt/2; ++qp) {
        if (tid < 128) {
            const int tr2 = tid >> 6, d = tid & 63;
            q_lds[tr2][d] = q[(size_t)(bl*Tt + qp*2 + tr2) * Dd + h*DHh + d];
        }
        __syncthreads();
        const int r = qp*2 + tr;
        float s = 0.f;
        #pragma unroll
        for (int d = 0; d < DHh; ++d) s += q_lds[tr][d] * k_lds[tc][d];
        s = s * SCALE + biasb[((size_t)(bg*Tt) + r) * Tt + tc] + maskv[tc];
        sc[tr][tc] = s;
        __syncthreads();
        if (tc < 64) {   // one wave per q-row: softmax + PV
            float s0 = sc[tr][tc], s1 = sc[tr][tc + 64];
            float m = fmaxf(s0, s1);
            for (int mm = 32; mm >= 1; mm >>= 1) m = fmaxf(m, __shfl_xor(m, mm));
            const float e0 = expf(s0 - m), e1 = expf(s1 - m);
            sc[tr][tc] = e0; sc[tr][tc + 64] = e1;
            float ssum = e0 + e1;
            for (int mm = 32; mm >= 1; mm >>= 1) ssum += __shfl_xor(ssum, mm);
            const float inv = 1.0f / ssum;
            const float* vb = v + (size_t)(bl*Tt) * Dd + h*DHh + tc;  // d = tc
            float acc = 0.f;
            #pragma unroll 4
            for (int j = 0; j < Tt; ++j) acc += sc[tr][j] * vb[(size_t)j * Dd];
            const bfpair p = splitbf(acc * inv);
            const size_t oo = (size_t)(bg*Tt + r) * Dd + h*DHh + tc;
            outh[oo] = p.h;
            outl[oo] = p.l;
        }
        __syncthreads();
    }
}

// ---------------------------------------------------------------------------
// out = LayerNorm((xh+xl) + res)*g + b.  Writes split (if outh) and f32 (if
// outf).  One wave per token.
__global__ __launch_bounds__(256) void add_ln_kernel(
    const u16* __restrict__ xh, const u16* __restrict__ xl,
    const float* __restrict__ res,
    const float* __restrict__ g, const float* __restrict__ bb,
    float* __restrict__ outf, u16* __restrict__ outh, u16* __restrict__ outl)
{
    const int tid = threadIdx.x;
    const int token = blockIdx.x * 4 + (tid >> 6);
    const int lane = tid & 63;
    const size_t base = (size_t)token * Dd + lane * 8;
    const u16x4 xh0 = *(const u16x4*)(xh + base);
    const u16x4 xh1 = *(const u16x4*)(xh + base + 4);
    const u16x4 xl0 = *(const u16x4*)(xl + base);
    const u16x4 xl1 = *(const u16x4*)(xl + base + 4);
    const float4 r0 = *(const float4*)(res + base);
    const float4 r1 = *(const float4*)(res + base + 4);
    const float v0 = bf2f(xh0.x)+bf2f(xl0.x)+r0.x;
    const float v1 = bf2f(xh0.y)+bf2f(xl0.y)+r0.y;
    const float v2 = bf2f(xh0.z)+bf2f(xl0.z)+r0.z;
    const float v3 = bf2f(xh0.w)+bf2f(xl0.w)+r0.w;
    const float v4 = bf2f(xh1.x)+bf2f(xl1.x)+r1.x;
    const float v5 = bf2f(xh1.y)+bf2f(xl1.y)+r1.y;
    const float v6 = bf2f(xh1.z)+bf2f(xl1.z)+r1.z;
    const float v7 = bf2f(xh1.w)+bf2f(xl1.w)+r1.w;
    float s1 = v0+v1+v2+v3+v4+v5+v6+v7;
    float s2 = v0*v0+v1*v1+v2*v2+v3*v3+v4*v4+v5*v5+v6*v6+v7*v7;
    for (int mm = 32; mm >= 1; mm >>= 1) {
        s1 += __shfl_xor(s1, mm);
        s2 += __shfl_xor(s2, mm);
    }
    const float mean = s1 * (1.0f / Dd);
    const float var  = s2 * (1.0f / Dd) - mean * mean;
    const float rstd = 1.0f / sqrtf(var + LN_EPS);
    const float4 g0 = *(const float4*)(g + lane*8);
    const float4 g1 = *(const float4*)(g + lane*8 + 4);
    const float4 b0 = *(const float4*)(bb + lane*8);
    const float4 b1 = *(const float4*)(bb + lane*8 + 4);
    float4 o0, o1;
    o0.x = (v0-mean)*rstd*g0.x + b0.x; o0.y = (v1-mean)*rstd*g0.y + b0.y;
    o0.z = (v2-mean)*rstd*g0.z + b0.z; o0.w = (v3-mean)*rstd*g0.w + b0.w;
    o1.x = (v4-mean)*rstd*g1.x + b1.x; o1.y = (v5-mean)*rstd*g1.y + b1.y;
    o1.z = (v6-mean)*rstd*g1.z + b1.z; o1.w = (v7-mean)*rstd*g1.w + b1.w;
    if (outf) {
        *(float4*)(outf + base)     = o0;
        *(float4*)(outf + base + 4) = o1;
    }
    if (outh) {
        const bfpair p0 = splitbf(o0.x), p1 = splitbf(o0.y);
        const bfpair p2 = splitbf(o0.z), p3 = splitbf(o0.w);
        const bfpair p4 = splitbf(o1.x), p5 = splitbf(o1.y);
        const bfpair p6 = splitbf(o1.z), p7 = splitbf(o1.w);
        u16x4 h0, l0, h1, l1;
        h0.x = p0.h; h0.y = p1.h; h0.z = p2.h; h0.w = p3.h;
        l0.x = p0.l; l0.y = p1.l; l0.z = p2.l; l0.w = p3.l;
        h1.x = p4.h; h1.y = p5.h; h1.z = p6.h; h1.w = p7.h;
        l1.x = p4.l; l1.y = p5.l; l1.z = p6.l; l1.w = p7.l;
        *(u16x4*)(outh + base)     = h0;
        *(u16x4*)(outh + base + 4) = h1;
        *(u16x4*)(outl + base)     = l0;
        *(u16x4*)(outl + base + 4) = l1;
    }
}

// ---------------------------------------------------------------------------
// gates = softmax((xh+xl) @ Wg + bg) over E=4; keep top-2 (lowest-index ties)
__global__ __launch_bounds__(256) void gates_kernel(
    const u16* __restrict__ xh, const u16* __restrict__ xl,
    const float* __restrict__ Wg, const float* __restrict__ bgp,
    float* __restrict__ w)
{
    const int tid = threadIdx.x;
    const int token = blockIdx.x * 4 + (tid >> 6);
    const int lane = tid & 63;
    const float4* Wg4 = (const float4*)Wg;
    const size_t tb = (size_t)token * Dd;
    float a0 = 0, a1 = 0, a2 = 0, a3 = 0;
    #pragma unroll
    for (int i = 0; i < Dd/64; ++i) {
        const int d = lane + i*64;
        const float xv = bf2f(xh[tb + d]) + bf2f(xl[tb + d]);
        const float4 wv = Wg4[d];
        a0 += xv*wv.x; a1 += xv*wv.y; a2 += xv*wv.z; a3 += xv*wv.w;
    }
    for (int mm = 32; mm >= 1; mm >>= 1) {
        a0 += __shfl_xor(a0, mm); a1 += __shfl_xor(a1, mm);
        a2 += __shfl_xor(a2, mm); a3 += __shfl_xor(a3, mm);
    }
    if (lane == 0) {
        float p[4] = {a0 + bgp[0], a1 + bgp[1], a2 + bgp[2], a3 + bgp[3]};
        const float mx = fmaxf(fmaxf(p[0], p[1]), fmaxf(p[2], p[3]));
        float s = 0.f;
        #pragma unroll
        for (int e = 0; e < 4; ++e) { p[e] = expf(p[e] - mx); s += p[e]; }
        const float invs = 1.0f / s;
        #pragma unroll
        for (int e = 0; e < 4; ++e) p[e] *= invs;
        int i1 = 0; float bv1 = p[0];
        for (int e = 1; e < 4; ++e) if (p[e] > bv1) { bv1 = p[e]; i1 = e; }
        int i2 = -1; float bv2 = -1.f;
        for (int e = 0; e < 4; ++e)
            if (e != i1 && p[e] > bv2) { bv2 = p[e]; i2 = e; }
        float4 ow;
        ow.x = (i1 == 0 || i2 == 0) ? p[0] : 0.f;
        ow.y = (i1 == 1 || i2 == 1) ? p[1] : 0.f;
        ow.z = (i1 == 2 || i2 == 2) ? p[2] : 0.f;
        ow.w = (i1 == 3 || i2 == 3) ? p[3] : 0.f;
        *(float4*)(w + (size_t)token * 4) = ow;
    }
}

// ---------------------------------------------------------------------------
extern "C" void kernel_launch(void* const* d_in, const int* in_sizes, int n_in,
                              void* d_out, int out_size, void* d_ws, size_t ws_size,
                              hipStream_t stream)
{
    (void)in_sizes; (void)n_in; (void)out_size; (void)ws_size;
    const int*   src   = (const int*)d_in[0];
    const float* frac  = (const float*)d_in[1];
    const float* cbfv  = (const float*)d_in[2];
    const float* Wemb  = (const float*)d_in[3];
    const float* bemb  = (const float*)d_in[4];
    const float* Wq    = (const float*)d_in[5];
    const float* bq    = (const float*)d_in[6];
    const float* Wk    = (const float*)d_in[7];
    const float* bk    = (const float*)d_in[8];
    const float* Wv    = (const float*)d_in[9];
    const float* bv    = (const float*)d_in[10];
    const float* Wo    = (const float*)d_in[11];
    const float* bo    = (const float*)d_in[12];
    const float* alpha = (const float*)d_in[13];
    const float* ln1g  = (const float*)d_in[14];
    const float* ln1b  = (const float*)d_in[15];
    const float* ln2g  = (const float*)d_in[16];
    const float* ln2b  = (const float*)d_in[17];
    const float* Wg    = (const float*)d_in[18];
    const float* bg    = (const float*)d_in[19];
    const float* W1    = (const float*)d_in[20];
    const float* b1    = (const float*)d_in[21];
    const float* W2    = (const float*)d_in[22];
    const float* b2    = (const float*)d_in[23];
    float* out = (float*)d_out;

    char* ws = (char*)d_ws;
    size_t o = 0;
    auto alloc = [&](size_t bytes) -> void* {
        char* p = ws + o;
        o += (bytes + 255) & ~(size_t)255;
        return (void*)p;
    };
    // total ~197.6 MB (< 210.2 MB proven-good in Round 3)
    float* table  = (float*)alloc((size_t)120 * 512 * 4);
    u16*   xbh    = (u16*)  alloc((size_t)MT * Dd * 2);
    u16*   xbl    = (u16*)  alloc((size_t)MT * Dd * 2);
    float* qc     = (float*)alloc((size_t)CHM * Dd * 4);  // ┐ contiguous; MoE
    float* kc     = (float*)alloc((size_t)CHM * Dd * 4);  // │ h split chunk
    float* vc     = (float*)alloc((size_t)CHM * Dd * 4);  // │ aliases here
    u16*   attnbh = (u16*)  alloc((size_t)MT * Dd * 2);   // │ (67.1 of 83.9MB)
    u16*   attnbl = (u16*)  alloc((size_t)MT * Dd * 2);   // ┘
    float* proj   = (float*)alloc((size_t)MT * Dd * 4);   // reused as ff
    float* biasb  = (float*)alloc((size_t)Bq * Tt * Tt * 4);
    float* wbuf   = (float*)alloc((size_t)MT * Ee * 4);
    u16*   wqTh   = (u16*)  alloc((size_t)512 * 512 * 2);
    u16*   wqTl   = (u16*)  alloc((size_t)512 * 512 * 2);
    u16*   wkTh   = (u16*)  alloc((size_t)512 * 512 * 2);
    u16*   wkTl   = (u16*)  alloc((size_t)512 * 512 * 2);
    u16*   wvTh   = (u16*)  alloc((size_t)512 * 512 * 2);
    u16*   wvTl   = (u16*)  alloc((size_t)512 * 512 * 2);
    u16*   woTh   = (u16*)  alloc((size_t)512 * 512 * 2);
    u16*   woTl   = (u16*)  alloc((size_t)512 * 512 * 2);
    u16*   w1Th   = (u16*)  alloc((size_t)Ee * FFf * Dd * 2);  // [e][FF][D]
    u16*   w1Tl   = (u16*)  alloc((size_t)Ee * FFf * Dd * 2);
    u16*   w2Th   = (u16*)  alloc((size_t)Ee * Dd * FFf * 2);  // [e][D][FF]
    u16*   w2Tl   = (u16*)  alloc((size_t)Ee * Dd * FFf * 2);
    // per-chunk h split (CHM x FF, 33.55 MB each) aliases dead qc..attnbh
    u16*   hbh    = (u16*)qc;
    u16*   hbl    = hbh + (size_t)CHM * FFf;
    float* ffb    = proj;   // proj dead after ln1

    // ---- prep ----
    emb_table_kernel<<<240, 256, 0, stream>>>(cbfv, Wemb, bemb, table);
    gather_kernel<<<8192, 256, 0, stream>>>(src, table, xbh, xbl);
    bias_kernel<<<8192, 256, 0, stream>>>(frac, alpha, biasb);
    const dim3 tb(32, 8);
    transpose_split<<<dim3(16, 16), tb, 0, stream>>>(Wq, wqTh, wqTl, 512, 512);
    transpose_split<<<dim3(16, 16), tb, 0, stream>>>(Wk, wkTh, wkTl, 512, 512);
    transpose_split<<<dim3(16, 16), tb, 0, stream>>>(Wv, wvTh, wvTl, 512, 512);
    transpose_split<<<dim3(16, 16), tb, 0, stream>>>(Wo, woTh, woTl, 512, 512);
    for (int e = 0; e < Ee; ++e) {
        transpose_split<<<dim3(64, 16), tb, 0, stream>>>(
            W1 + (size_t)e * Dd * FFf,
            w1Th + (size_t)e * FFf * Dd, w1Tl + (size_t)e * FFf * Dd, Dd, FFf);
        transpose_split<<<dim3(16, 64), tb, 0, stream>>>(
            W2 + (size_t)e * FFf * Dd,
            w2Th + (size_t)e * Dd * FFf, w2Tl + (size_t)e * Dd * FFf, FFf, Dd);
    }

    for (int layer = 0; layer < 3; ++layer) {
        // attention in two 64-batch chunks (q/k/v are chunk-sized)
        for (int c = 0; c < 2; ++c) {
            const size_t coff = (size_t)c * CHM * Dd;
            gemm_split<0><<<dim3(4,64), 256, 0, stream>>>(
                xbh + coff, xbl + coff, wqTh, wqTl, bq, qc, nullptr,
                CHM, 512, 512, nullptr, 0);
            gemm_split<0><<<dim3(4,64), 256, 0, stream>>>(
                xbh + coff, xbl + coff, wkTh, wkTl, bk, kc, nullptr,
                CHM, 512, 512, nullptr, 0);
            gemm_split<0><<<dim3(4,64), 256, 0, stream>>>(
                xbh + coff, xbl + coff, wvTh, wvTl, bv, vc, nullptr,
                CHM, 512, 512, nullptr, 0);
            attn_kernel<<<(Bq/2)*Hh, 256, 0, stream>>>(
                qc, kc, vc, biasb, src, attnbh, attnbl, c * (Bq/2));
        }
        gemm_split<0><<<dim3(4,128), 256, 0, stream>>>(
            attnbh, attnbl, woTh, woTl, bo, proj, nullptr, MT, 512, 512, nullptr, 0);
        add_ln_kernel<<<4096, 256, 0, stream>>>(
            xbh, xbl, proj, ln1g, ln1b, nullptr, xbh, xbl);
        gates_kernel<<<4096, 256, 0, stream>>>(xbh, xbl, Wg, bg, wbuf);
        // MoE in two token chunks (h split chunk aliases dead q/k/v region)
        for (int c = 0; c < 2; ++c) {
            const size_t coff = (size_t)c * CHM * Dd;
            for (int e = 0; e < Ee; ++e) {
                gemm_split<1><<<dim3(16,64), 256, 0, stream>>>(
                    xbh + coff, xbl + coff,
                    w1Th + (size_t)e * FFf * Dd, w1Tl + (size_t)e * FFf * Dd,
                    b1 + e * FFf, hbh, hbl, CHM, FFf, Dd, nullptr, 0);
                if (e == 0)
                    gemm_split<3><<<dim3(4,64), 256, 0, stream>>>(
                        hbh, hbl,
                        w2Th + (size_t)e * Dd * FFf, w2Tl + (size_t)e * Dd * FFf,
                        b2 + e * Dd, ffb + coff, nullptr, CHM, Dd, FFf,
                        wbuf + (size_t)c * CHM * Ee + e, Ee);
                else
                    gemm_split<2><<<dim3(4,64), 256, 0, stream>>>(
                        hbh, hbl,
                        w2Th + (size_t)e * Dd * FFf, w2Tl + (size_t)e * Dd * FFf,
                        b2 + e * Dd, ffb + coff, nullptr, CHM, Dd, FFf,
                        wbuf + (size_t)c * CHM * Ee + e, Ee);
            }
        }
        if (layer == 2)
            add_ln_kernel<<<4096, 256, 0, stream>>>(
                xbh, xbl, ffb, ln2g, ln2b, out, nullptr, nullptr);
        else
            add_ln_kernel<<<4096, 256, 0, stream>>>(
                xbh, xbl, ffb, ln2g, ln2b, nullptr, xbh, xbl);
    }
}